// Round 6
// baseline (1233.469 us; speedup 1.0000x reference)
//
#include <hip/hip_runtime.h>
#include <hip/hip_bf16.h>
#include <cstdint>

#define SLOPE 0.2f
#define IN_F 256
#define HD 128    // H*D
#define BSH 10    // bucket shift: bucket = dst >> 10
#define NBP 256   // padded bucket count (supports Nn up to 256K)
#define CHUNK 4096

typedef __attribute__((ext_vector_type(8))) short bf16x8;
typedef __attribute__((ext_vector_type(4))) float f32x4;

union BF8 { bf16x8 v; __hip_bfloat16 h[8]; };

__device__ inline float bf_lo(unsigned u) { unsigned w = u << 16; return __builtin_bit_cast(float, w); }
__device__ inline float bf_hi(unsigned u) { unsigned w = u & 0xffff0000u; return __builtin_bit_cast(float, w); }

__device__ __forceinline__ void unpack8(uint4 u, float* x) {
    x[0] = bf_lo(u.x); x[1] = bf_hi(u.x);
    x[2] = bf_lo(u.y); x[3] = bf_hi(u.y);
    x[4] = bf_lo(u.z); x[5] = bf_hi(u.z);
    x[6] = bf_lo(u.w); x[7] = bf_hi(u.w);
}

// ---------------------------------------------------------------------------
// Dtype detector (safety net; measured flag==1 -> bf16 on this bench).
// ---------------------------------------------------------------------------
__global__ void detect_kernel(const unsigned int* __restrict__ xw,
                              int* __restrict__ flag) {
    __shared__ int sh[256];
    int t = threadIdx.x;
    int cnt = 0;
    for (int i = t; i < 4096; i += 256) {
        unsigned e = (xw[i] >> 7) & 0xFF;
        cnt += (e >= 64u && e <= 191u) ? 1 : 0;
    }
    sh[t] = cnt;
    __syncthreads();
    for (int s = 128; s > 0; s >>= 1) {
        if (t < s) sh[t] += sh[t + s];
        __syncthreads();
    }
    if (t == 0) flag[0] = (sh[0] > 3300) ? 1 : 0;
}

// ---------------------------------------------------------------------------
// Prep: pack weights into bf16 MFMA B-fragment order + biases/attn to f32.
// ---------------------------------------------------------------------------
__global__ void prep_kernel(const void* __restrict__ Ws, const void* __restrict__ Wd,
                            const void* __restrict__ Wr,
                            const void* __restrict__ bs, const void* __restrict__ bd,
                            const void* __restrict__ br,
                            const void* __restrict__ attn,
                            const int* __restrict__ flag,
                            __hip_bfloat16* __restrict__ Wp,
                            float* __restrict__ bfv, float* __restrict__ af) {
    int t = blockIdx.x * blockDim.x + threadIdx.x;
    int isb = flag[0];
    if (t < 3 * 8 * 8 * 64) {
        int lane = t & 63;
        int nt = (t >> 6) & 7;
        int kt = (t >> 9) & 7;
        int m  = t >> 12;
        const void* W = (m == 0) ? Ws : (m == 1) ? Wd : Wr;
        int n = nt * 16 + (lane & 15);
        int k0 = kt * 32 + (lane >> 4) * 8;
        size_t off = ((((size_t)m * 8 + kt) * 8 + nt) * 64 + lane) * 8;
#pragma unroll
        for (int j = 0; j < 8; j++) {
            size_t gi = (size_t)(k0 + j) * HD + n;
            Wp[off + j] = isb ? ((const __hip_bfloat16*)W)[gi]
                              : __float2bfloat16(((const float*)W)[gi]);
        }
    } else if (t < 3 * 8 * 8 * 64 + 384) {
        int j = t - 3 * 8 * 8 * 64;
        const void* b = (j < 128) ? bs : (j < 256 ? bd : br);
        int i = j & 127;
        bfv[j] = isb ? __bfloat162float(((const __hip_bfloat16*)b)[i])
                     : ((const float*)b)[i];
    } else if (t < 3 * 8 * 8 * 64 + 384 + 128) {
        int j = t - 3 * 8 * 8 * 64 - 384;
        af[j] = isb ? __bfloat162float(((const __hip_bfloat16*)attn)[j])
                    : ((const float*)attn)[j];
    }
}

// ---------------------------------------------------------------------------
// Fused MFMA projection, LDS-staged weights (unchanged from round 5).
// ---------------------------------------------------------------------------
template <bool ISB>
__device__ __forceinline__ void proj_body(
    const void* __restrict__ xv, const __hip_bfloat16* __restrict__ Wp,
    const float* __restrict__ bfv,
    __hip_bfloat16* __restrict__ el, __hip_bfloat16* __restrict__ er,
    __hip_bfloat16* __restrict__ resm,
    __hip_bfloat16* __restrict__ sbuf, int Nn) {
    int wv = threadIdx.x >> 6;
    int lane = threadIdx.x & 63;
    int r_base = blockIdx.x * 128 + wv * 32;

    BF8 a[2][8];
#pragma unroll
    for (int j = 0; j < 2; j++) {
        int row = r_base + j * 16 + (lane & 15);
        if (row >= Nn) row = Nn - 1;
        size_t xo = (size_t)row * IN_F + (lane >> 4) * 8;
#pragma unroll
        for (int kt = 0; kt < 8; kt++) {
            if (ISB) {
                a[j][kt].v = *(const bf16x8*)((const __hip_bfloat16*)xv + xo + kt * 32);
            } else {
                float4 p0 = *(const float4*)((const float*)xv + xo + kt * 32);
                float4 p1 = *(const float4*)((const float*)xv + xo + kt * 32 + 4);
                a[j][kt].h[0] = __float2bfloat16(p0.x); a[j][kt].h[1] = __float2bfloat16(p0.y);
                a[j][kt].h[2] = __float2bfloat16(p0.z); a[j][kt].h[3] = __float2bfloat16(p0.w);
                a[j][kt].h[4] = __float2bfloat16(p1.x); a[j][kt].h[5] = __float2bfloat16(p1.y);
                a[j][kt].h[6] = __float2bfloat16(p1.z); a[j][kt].h[7] = __float2bfloat16(p1.w);
            }
        }
    }

    int col = lane & 15;
    int quad = lane >> 4;

    for (int m = 0; m < 3; m++) {
        f32x4 acc[2][8];
#pragma unroll
        for (int j = 0; j < 2; j++)
#pragma unroll
            for (int nt = 0; nt < 8; nt++) acc[j][nt] = (f32x4){0.f, 0.f, 0.f, 0.f};

        for (int h = 0; h < 2; h++) {
            __syncthreads();
#pragma unroll
            for (int i = 0; i < 8; i++) {
                int chunk = i * 256 + threadIdx.x;
                *(bf16x8*)(sbuf + (size_t)chunk * 8) =
                    *(const bf16x8*)(Wp + (size_t)m * 32768 + (size_t)h * 16384 + (size_t)chunk * 8);
            }
            __syncthreads();
#pragma unroll
            for (int k4 = 0; k4 < 4; k4++) {
#pragma unroll
                for (int nt = 0; nt < 8; nt++) {
                    bf16x8 b = *(const bf16x8*)(sbuf + ((size_t)(k4 * 8 + nt)) * 512 + (size_t)lane * 8);
                    acc[0][nt] = __builtin_amdgcn_mfma_f32_16x16x32_bf16(a[0][h * 4 + k4].v, b, acc[0][nt], 0, 0, 0);
                    acc[1][nt] = __builtin_amdgcn_mfma_f32_16x16x32_bf16(a[1][h * 4 + k4].v, b, acc[1][nt], 0, 0, 0);
                }
            }
        }

        __hip_bfloat16* outp = (m == 0) ? el : (m == 1) ? er : resm;
#pragma unroll
        for (int j = 0; j < 2; j++) {
#pragma unroll
            for (int nt = 0; nt < 8; nt++) {
                float bv = bfv[m * HD + nt * 16 + col];
#pragma unroll
                for (int r = 0; r < 4; r++) {
                    int row = r_base + j * 16 + quad * 4 + r;
                    if (row < Nn)
                        outp[(size_t)row * HD + nt * 16 + col] = __float2bfloat16(acc[j][nt][r] + bv);
                }
            }
        }
    }
}

__global__ __launch_bounds__(256) void proj_mfma_kernel(
    const void* __restrict__ xv, const __hip_bfloat16* __restrict__ Wp,
    const float* __restrict__ bfv, const int* __restrict__ flag,
    __hip_bfloat16* __restrict__ el, __hip_bfloat16* __restrict__ er,
    __hip_bfloat16* __restrict__ resm, int Nn) {
    __shared__ __hip_bfloat16 sbuf[16384];   // 32 KB
    if (flag[0]) proj_body<true>(xv, Wp, bfv, el, er, resm, sbuf, Nn);
    else         proj_body<false>(xv, Wp, bfv, el, er, resm, sbuf, Nn);
}

// ---------------------------------------------------------------------------
// Bucketed CSR build. Buckets of 1024 nodes (b = dst>>10) keep each bucket's
// edge region ~64 KB so the final scatter stays cache-local.
// ---------------------------------------------------------------------------
__global__ void hist_kernel(const int* __restrict__ dst, int* __restrict__ deg, int E) {
    int t = blockIdx.x * blockDim.x + threadIdx.x;
    if (t < E) atomicAdd(&deg[dst[t]], 1);
}

__global__ void bucket_cnt_kernel(const int* __restrict__ deg, int* __restrict__ bcnt, int Nn) {
    int v = blockIdx.x * blockDim.x + threadIdx.x;
    if (v < Nn) atomicAdd(&bcnt[v >> BSH], deg[v]);
}

// single block, NBP threads: exclusive scan of bucket counts -> cursors
__global__ void scan_kernel(const int* __restrict__ bcnt, int* __restrict__ scur,
                            int* __restrict__ bcur, int nb) {
    __shared__ int sh[NBP];
    int t = threadIdx.x;
    int myc = (t < nb) ? bcnt[t] : 0;
    sh[t] = myc;
    __syncthreads();
    for (int off = 1; off < NBP; off <<= 1) {
        int v = (t >= off) ? sh[t - off] : 0;
        __syncthreads();
        sh[t] += v;
        __syncthreads();
    }
    if (t < nb) {
        int excl = sh[t] - myc;
        scur[t] = excl;
        bcur[t] = excl;
    }
}

__global__ void alloc_kernel(const int* __restrict__ deg, int* __restrict__ base,
                             int* __restrict__ cursor, int* __restrict__ bcur, int Nn) {
    int v = blockIdx.x * blockDim.x + threadIdx.x;
    if (v < Nn) {
        int b = atomicAdd(&bcur[v >> BSH], deg[v]);
        base[v] = b;
        cursor[v] = b;
    }
}

// Pass 1: partition edges into bucket-contiguous staged (dst,src) pairs.
// LDS histogram + scan + redistribute -> coalesced run writes (~340 B avg).
__global__ __launch_bounds__(256) void pass1_kernel(
    const int* __restrict__ src, const int* __restrict__ dst,
    int* __restrict__ scur, unsigned long long* __restrict__ staged, int E) {
    __shared__ unsigned int hist[NBP], scanx[NBP], cnt2[NBP];
    __shared__ int gbase[NBP];
    __shared__ unsigned long long pairs[CHUNK];
    int t = threadIdx.x;
    int e0 = blockIdx.x * CHUNK;
    int nE = E - e0; if (nE > CHUNK) nE = CHUNK;

    for (int i = t; i < NBP; i += 256) { hist[i] = 0; cnt2[i] = 0; }
    __syncthreads();
    // sweep A: count
    for (int i = t; i < nE; i += 256)
        atomicAdd(&hist[dst[e0 + i] >> BSH], 1u);
    __syncthreads();
    // block-local exclusive scan (Hillis-Steele inclusive, then subtract)
    unsigned myh = hist[t];
    scanx[t] = myh;
    __syncthreads();
    for (int off = 1; off < NBP; off <<= 1) {
        unsigned v = (t >= off) ? scanx[t - off] : 0u;
        __syncthreads();
        scanx[t] += v;
        __syncthreads();
    }
    unsigned excl = scanx[t] - myh;
    // reserve global run per bucket
    int rb = myh ? atomicAdd(&scur[t], (int)myh) : 0;
    gbase[t] = rb - (int)excl;
    __syncthreads();
    scanx[t] = excl;   // store exclusive offsets for sweep B
    __syncthreads();
    // sweep B: redistribute into LDS bucket-major order
    for (int i = t; i < nE; i += 256) {
        int d = dst[e0 + i];
        int s = src[e0 + i];
        int b = d >> BSH;
        unsigned r = atomicAdd(&cnt2[b], 1u);
        pairs[scanx[b] + r] = ((unsigned long long)(unsigned)d << 32) | (unsigned)s;
    }
    __syncthreads();
    // write out: consecutive slots are mostly same bucket -> coalesced runs
    for (int i = t; i < nE; i += 256) {
        unsigned long long p = pairs[i];
        int b = (int)(p >> (32 + BSH));
        staged[(size_t)(gbase[b] + i)] = p;
    }
}

// Pass 2: linear read of staged pairs; scatter src within its own bucket's
// <=64 KB window (L2-absorbed, full-line writebacks).
__global__ void pass2_kernel(const unsigned long long* __restrict__ staged,
                             int* __restrict__ cursor,
                             int* __restrict__ srcs_sorted, int E) {
    int t = blockIdx.x * blockDim.x + threadIdx.x;
    if (t < E) {
        unsigned long long p = staged[t];
        int d = (int)(p >> 32);
        int s = (int)(p & 0xffffffffu);
        int pos = atomicAdd(&cursor[d], 1);
        srcs_sorted[pos] = s;
    }
}

// ---------------------------------------------------------------------------
// Fused per-node softmax aggregation + residual. One wave per node; each
// 16-lane quarter handles one edge (8 ch/lane, uint4 = full 256B row per
// quarter). 4 edges in flight/iter; head reduce = ONE shfl_xor(1);
// cross-quarter combine once per node. No max-subtraction (scores O(1),
// verified rounds 3-5).
// ---------------------------------------------------------------------------
__global__ __launch_bounds__(256) void node_agg_kernel(
    const uint4* __restrict__ el4,
    const uint4* __restrict__ er4,
    const uint4* __restrict__ res4,
    const float* __restrict__ af,
    const int* __restrict__ base,
    const int* __restrict__ deg,
    const int* __restrict__ srcs_sorted,
    const int* __restrict__ flag,
    void* __restrict__ out,
    int Nn) {
    int wv = threadIdx.x >> 6;
    int lane = threadIdx.x & 63;
    int v = blockIdx.x * 4 + wv;
    if (v >= Nn) return;
    int q = lane & 15;      // word-quad within row (ch 8q..8q+7)
    int Q = lane >> 4;      // quarter id = edge slot within iteration

    float er_[8], a_[8];
    unpack8(er4[(size_t)v * 16 + q], er_);
    float4 a0 = *(const float4*)(af + 8 * q);
    float4 a1 = *(const float4*)(af + 8 * q + 4);
    a_[0] = a0.x; a_[1] = a0.y; a_[2] = a0.z; a_[3] = a0.w;
    a_[4] = a1.x; a_[5] = a1.y; a_[6] = a1.z; a_[7] = a1.w;

    int b0 = base[v];
    int dv = deg[v];

    float l = 0.f;
    float acc[8];
#pragma unroll
    for (int j = 0; j < 8; j++) acc[j] = 0.f;

    for (int i0 = 0; i0 < dv; i0 += 64) {
        int chunk = dv - i0; if (chunk > 64) chunk = 64;
        int idx = (lane < chunk) ? srcs_sorted[b0 + i0 + lane] : 0;
        for (int i = 0; i < chunk; i += 4) {
            int e = i + Q;
            int s = __shfl(idx, (e < 64) ? e : 0);
            if (e < chunk) {
                float x[8];
                unpack8(el4[(size_t)s * 16 + q], x);
                float p = 0.f;
#pragma unroll
                for (int j = 0; j < 8; j++) {
                    float tt = x[j] + er_[j];
                    tt = fmaxf(tt, SLOPE * tt);
                    p = fmaf(tt, a_[j], p);
                }
                p += __shfl_xor(p, 1);   // head = 16 ch = 2 lanes
                float w = __expf(p);
                l += w;
#pragma unroll
                for (int j = 0; j < 8; j++) acc[j] = fmaf(w, x[j], acc[j]);
            }
        }
    }

    // combine quarters (lanes with equal q hold the same channels)
    l += __shfl_xor(l, 16); l += __shfl_xor(l, 32);
#pragma unroll
    for (int j = 0; j < 8; j++) {
        acc[j] += __shfl_xor(acc[j], 16);
        acc[j] += __shfl_xor(acc[j], 32);
    }

    if (Q == 0) {
        float inv = (dv > 0 && l > 0.f) ? (1.f / l) : 0.f;
        float r[8];
        unpack8(res4[(size_t)v * 16 + q], r);
        float o[8];
#pragma unroll
        for (int j = 0; j < 8; j++) o[j] = acc[j] * inv + r[j];
        if (flag[0]) {
            uint4 pk;
            unsigned w0, w1, w2, w3;
            w0 = (unsigned)__builtin_bit_cast(unsigned short, __float2bfloat16(o[0]))
               | ((unsigned)__builtin_bit_cast(unsigned short, __float2bfloat16(o[1])) << 16);
            w1 = (unsigned)__builtin_bit_cast(unsigned short, __float2bfloat16(o[2]))
               | ((unsigned)__builtin_bit_cast(unsigned short, __float2bfloat16(o[3])) << 16);
            w2 = (unsigned)__builtin_bit_cast(unsigned short, __float2bfloat16(o[4]))
               | ((unsigned)__builtin_bit_cast(unsigned short, __float2bfloat16(o[5])) << 16);
            w3 = (unsigned)__builtin_bit_cast(unsigned short, __float2bfloat16(o[6]))
               | ((unsigned)__builtin_bit_cast(unsigned short, __float2bfloat16(o[7])) << 16);
            pk.x = w0; pk.y = w1; pk.z = w2; pk.w = w3;
            ((uint4*)out)[(size_t)v * 16 + q] = pk;
        } else {
            float4 f0 = make_float4(o[0], o[1], o[2], o[3]);
            float4 f1 = make_float4(o[4], o[5], o[6], o[7]);
            ((float4*)out)[(size_t)v * 32 + 2 * q]     = f0;
            ((float4*)out)[(size_t)v * 32 + 2 * q + 1] = f1;
        }
    }
}

// ---------------------------------------------------------------------------
extern "C" void kernel_launch(void* const* d_in, const int* in_sizes, int n_in,
                              void* d_out, int out_size, void* d_ws, size_t ws_size,
                              hipStream_t stream) {
    const void* x    = d_in[0];
    const int*  src  = (const int*)d_in[1];
    const int*  dst  = (const int*)d_in[2];
    const void* Ws   = d_in[3];
    const void* bs   = d_in[4];
    const void* Wd   = d_in[5];
    const void* bd   = d_in[6];
    const void* attn = d_in[7];
    const void* Wr   = d_in[8];
    const void* br   = d_in[9];

    const int Nn = in_sizes[0] / IN_F;   // 100000
    const int E  = in_sizes[1];          // 1600000
    const int nb = (Nn + (1 << BSH) - 1) >> BSH;   // 98 buckets

    char* w = (char*)d_ws;
    auto take = [&](size_t bytes) {
        char* p = w;
        w += (bytes + 255) & ~(size_t)255;
        return p;
    };
    int*   flag = (int*)take(256);
    __hip_bfloat16* Wp = (__hip_bfloat16*)take((size_t)3 * 8 * 8 * 64 * 8 * 2);
    float* bfv  = (float*)take((size_t)384 * 4);
    float* af   = (float*)take((size_t)128 * 4);
    __hip_bfloat16* el   = (__hip_bfloat16*)take((size_t)Nn * HD * 2);
    __hip_bfloat16* er   = (__hip_bfloat16*)take((size_t)Nn * HD * 2);
    __hip_bfloat16* resm = (__hip_bfloat16*)take((size_t)Nn * HD * 2);
    int* deg     = (int*)take((size_t)Nn * 4);
    int* base    = (int*)take((size_t)Nn * 4);
    int* cursor  = (int*)take((size_t)Nn * 4);
    int* bcnt    = (int*)take((size_t)NBP * 4);
    int* scur    = (int*)take((size_t)NBP * 4);
    int* bcur    = (int*)take((size_t)NBP * 4);
    int* srcs_sorted = (int*)take((size_t)E * 4);
    // staged pairs alias el's buffer: pass1/pass2 finish before proj writes el
    unsigned long long* staged = (unsigned long long*)el;

    hipMemsetAsync(deg, 0, (size_t)Nn * 4, stream);
    hipMemsetAsync(bcnt, 0, (size_t)NBP * 4, stream);

    detect_kernel<<<1, 256, 0, stream>>>((const unsigned int*)x, flag);
    prep_kernel<<<(3 * 8 * 8 * 64 + 512 + 255) / 256, 256, 0, stream>>>(
        Ws, Wd, Wr, bs, bd, br, attn, flag, Wp, bfv, af);

    // CSR build (uses el buffer as staging; runs before proj)
    hist_kernel<<<(E + 255) / 256, 256, 0, stream>>>(dst, deg, E);
    bucket_cnt_kernel<<<(Nn + 255) / 256, 256, 0, stream>>>(deg, bcnt, Nn);
    scan_kernel<<<1, NBP, 0, stream>>>(bcnt, scur, bcur, nb);
    alloc_kernel<<<(Nn + 255) / 256, 256, 0, stream>>>(deg, base, cursor, bcur, Nn);
    pass1_kernel<<<(E + CHUNK - 1) / CHUNK, 256, 0, stream>>>(src, dst, scur, staged, E);
    pass2_kernel<<<(E + 255) / 256, 256, 0, stream>>>(staged, cursor, srcs_sorted, E);

    proj_mfma_kernel<<<(Nn + 127) / 128, 256, 0, stream>>>(
        x, Wp, bfv, flag, el, er, resm, Nn);

    node_agg_kernel<<<(Nn + 3) / 4, 256, 0, stream>>>(
        (const uint4*)el, (const uint4*)er, (const uint4*)resm,
        af, base, deg, srcs_sorted, flag, d_out, Nn);
}